// Round 2
// baseline (214.400 us; speedup 1.0000x reference)
//
#include <hip/hip_runtime.h>
#include <hip/hip_bf16.h>
#include <math.h>

typedef __hip_bfloat16 bf16;

__device__ __forceinline__ float b2f(bf16 v) { return __bfloat162float(v); }

template <bool F32>
__device__ __forceinline__ float ld(const void* p, int i) {
  if (F32) return ((const float*)p)[i];
  return b2f(((const bf16*)p)[i]);
}

__device__ __forceinline__ float sigm(float x) {
  return 0.5f * (1.0f + tanhf(0.5f * x));  // saturates cleanly, no inf
}

// ---------------------------------------------------------------------------
// K0: dtype detection. bf16 coords are in [0,1) -> every u16 has small
// exponent. f32 coords' low half-words are random mantissa bits -> some
// exponent >= 0x93 (|v| >= 2^20) with overwhelming probability.
// flag = 1 -> f32, 0 -> bf16.
// ---------------------------------------------------------------------------
__global__ void k_detect(const void* xabs, int* flag) {
  __shared__ int hit;
  if (threadIdx.x == 0) hit = 0;
  __syncthreads();
  unsigned short v = ((const unsigned short*)xabs)[threadIdx.x];  // 128 u16s
  int ex = (v >> 7) & 0xFF;
  if (ex >= 0x93) atomicOr(&hit, 1);
  __syncthreads();
  if (threadIdx.x == 0) *flag = hit ? 1 : 0;
}

// ---------------------------------------------------------------------------
// K1: Z[m, g*64+e] = sum_d h0[m,d] * Wsoc[e, g*128+d]
// grid (16 m-tiles, 64 g), block 256, 64x64 tile, 4x4 microtile,
// K chunked in 64s so LDS = 2*64*68*4 = 34 KB.
// ---------------------------------------------------------------------------
template <bool F32>
__device__ __forceinline__ void zgemm_body(const void* h0, const void* Wsoc,
                                           float* __restrict__ Z) {
  const int mt = blockIdx.x;  // 0..15
  const int g  = blockIdx.y;  // 0..63
  __shared__ __align__(16) float Asm[64][68];  // [d][m]
  __shared__ __align__(16) float Bsm[64][68];  // [d][e]
  const int tid = threadIdx.x;
  const int tm = tid & 15, te = tid >> 4;
  float acc[4][4] = {};
  for (int dc = 0; dc < 128; dc += 64) {
    for (int idx = tid; idx < 64 * 64; idx += 256) {
      int r = idx >> 6, d = idx & 63;
      Asm[d][r] = ld<F32>(h0, (mt * 64 + r) * 128 + dc + d);
      Bsm[d][r] = ld<F32>(Wsoc, r * 8192 + g * 128 + dc + d);
    }
    __syncthreads();
    for (int d = 0; d < 64; ++d) {
      float4 a = *reinterpret_cast<const float4*>(&Asm[d][tm * 4]);
      float4 b = *reinterpret_cast<const float4*>(&Bsm[d][te * 4]);
      float av[4] = {a.x, a.y, a.z, a.w};
      float bv[4] = {b.x, b.y, b.z, b.w};
#pragma unroll
      for (int i = 0; i < 4; ++i)
#pragma unroll
        for (int j = 0; j < 4; ++j) acc[i][j] += av[i] * bv[j];
    }
    __syncthreads();
  }
  const int m0 = mt * 64 + tm * 4;
  const int e0 = g * 64 + te * 4;
#pragma unroll
  for (int i = 0; i < 4; ++i) {
    float4 v = make_float4(acc[i][0], acc[i][1], acc[i][2], acc[i][3]);
    *reinterpret_cast<float4*>(&Z[(size_t)(m0 + i) * 4096 + e0]) = v;
  }
}

__global__ __launch_bounds__(256) void k_zgemm(const void* h0, const void* Wsoc,
                                               float* Z, const int* flag) {
  if (*flag) zgemm_body<true>(h0, Wsoc, Z);
  else       zgemm_body<false>(h0, Wsoc, Z);
}

// ---------------------------------------------------------------------------
// K2: per-n gather of Z rows by grid-cell + input embedding; one wave per n.
// X[n, 0:64]=relu(emb), [64:128]=relu(pool), [128:256]=h0[n,:].
// ---------------------------------------------------------------------------
template <bool F32>
__device__ __forceinline__ void gather_body(const void* xabs, const void* h0,
                                            const void* Wemb, const void* bemb,
                                            const void* bsoc,
                                            const float* __restrict__ Z,
                                            float* __restrict__ X) {
  const int lane = threadIdx.x & 63;
  const int n = blockIdx.x * 4 + (threadIdx.x >> 6);
  const float xn = ld<F32>(xabs, 2 * n);
  const float yn = ld<F32>(xabs, 2 * n + 1);
  const float tx = xn - 0.2f, ty = yn - 0.2f;
  float acc = 0.f;
  for (int mb = 0; mb < 16; ++mb) {
    const int m = mb * 64 + lane;
    float dx = ld<F32>(xabs, 2 * m) - tx;
    float dy = ld<F32>(xabs, 2 * m + 1) - ty;
    int cx = (int)floorf(dx / 0.4f * 8.0f);
    int cy = (int)floorf(dy / 0.4f * 8.0f);
    bool valid = (dx >= 0.f) & (dx < 0.4f) & (dy >= 0.f) & (dy < 0.4f) &
                 (cx >= 0) & (cx < 8) & (cy >= 0) & (cy < 8) & (m != n);
    int cell = cx + cy * 8;
    unsigned long long msk = __ballot(valid);
    while (msk) {
      int b = __builtin_ctzll(msk);
      msk &= msk - 1;
      int c = __shfl(cell, b);
      acc += Z[(size_t)(mb * 64 + b) * 4096 + c * 64 + lane];
    }
  }
  float pool = fmaxf(acc + ld<F32>(bsoc, lane), 0.f);
  float emb = fmaxf(ld<F32>(Wemb, lane * 2) * xn +
                        ld<F32>(Wemb, lane * 2 + 1) * yn + ld<F32>(bemb, lane),
                    0.f);
  float* Xn = X + (size_t)n * 256;
  Xn[lane] = emb;
  Xn[64 + lane] = pool;
  Xn[128 + lane] = ld<F32>(h0, n * 128 + lane);
  Xn[192 + lane] = ld<F32>(h0, n * 128 + 64 + lane);
}

__global__ __launch_bounds__(256) void k_gather(const void* xabs, const void* h0,
                                                const void* Wemb, const void* bemb,
                                                const void* bsoc, const float* Z,
                                                float* X, const int* flag) {
  if (*flag) gather_body<true>(xabs, h0, Wemb, bemb, bsoc, Z, X);
  else       gather_body<false>(xabs, h0, Wemb, bemb, bsoc, Z, X);
}

// ---------------------------------------------------------------------------
// K3: gates[1024x512] = X[1024x256] @ Bcat[256x512] + (b_ih + b_hh)
// Bcat[k,j] = W_ih[j,k] (k<128) else W_hh[j,k-128].  W_ih is [512,128].
// ---------------------------------------------------------------------------
template <bool F32>
__device__ __forceinline__ void gates_body(const float* __restrict__ X,
                                           const void* Wih, const void* Whh,
                                           const void* bih, const void* bhh,
                                           float* __restrict__ gates) {
  const int nt = blockIdx.x;  // 0..15
  const int jt = blockIdx.y;  // 0..7
  __shared__ __align__(16) float Asm[64][68];  // [k][n]
  __shared__ __align__(16) float Bsm[64][68];  // [k][j]
  const int tid = threadIdx.x;
  const int tm = tid & 15, te = tid >> 4;
  float acc[4][4] = {};
  for (int kc = 0; kc < 256; kc += 64) {
    for (int idx = tid; idx < 64 * 64; idx += 256) {
      int r = idx >> 6, k = idx & 63;
      Asm[k][r] = X[(size_t)(nt * 64 + r) * 256 + kc + k];
      int j = jt * 64 + r;
      int kg = kc + k;
      Bsm[k][r] = (kg < 128) ? ld<F32>(Wih, j * 128 + kg)
                             : ld<F32>(Whh, j * 128 + kg - 128);
    }
    __syncthreads();
    for (int k = 0; k < 64; ++k) {
      float4 a = *reinterpret_cast<const float4*>(&Asm[k][tm * 4]);
      float4 b = *reinterpret_cast<const float4*>(&Bsm[k][te * 4]);
      float av[4] = {a.x, a.y, a.z, a.w};
      float bv[4] = {b.x, b.y, b.z, b.w};
#pragma unroll
      for (int i = 0; i < 4; ++i)
#pragma unroll
        for (int j = 0; j < 4; ++j) acc[i][j] += av[i] * bv[j];
    }
    __syncthreads();
  }
  const int n0 = nt * 64 + tm * 4;
  const int j0 = jt * 64 + te * 4;
  float bsum[4];
#pragma unroll
  for (int j = 0; j < 4; ++j)
    bsum[j] = ld<F32>(bih, j0 + j) + ld<F32>(bhh, j0 + j);
#pragma unroll
  for (int i = 0; i < 4; ++i) {
    float4 v = make_float4(acc[i][0] + bsum[0], acc[i][1] + bsum[1],
                           acc[i][2] + bsum[2], acc[i][3] + bsum[3]);
    *reinterpret_cast<float4*>(&gates[(size_t)(n0 + i) * 512 + j0]) = v;
  }
}

__global__ __launch_bounds__(256) void k_gates(const float* X, const void* Wih,
                                               const void* Whh, const void* bih,
                                               const void* bhh, float* gates,
                                               const int* flag) {
  if (*flag) gates_body<true>(X, Wih, Whh, bih, bhh, gates);
  else       gates_body<false>(X, Wih, Whh, bih, bhh, gates);
}

// ---------------------------------------------------------------------------
// K4: LSTM elementwise + final = h @ W_out^T + b_out -> 6 chunks [1024,20].
// ---------------------------------------------------------------------------
template <bool F32>
__device__ __forceinline__ void lstm_body(const float* __restrict__ gates,
                                          const void* c0, const void* Wout,
                                          const void* bout, void* out) {
  const int n = blockIdx.x;
  const int t = threadIdx.x;  // 0..127
  __shared__ float hs[128];
  const float* gn = gates + (size_t)n * 512;
  float ig = gn[t], fg = gn[128 + t], gg = gn[256 + t], og = gn[384 + t];
  float si = sigm(ig), sf = sigm(fg), so = sigm(og);
  float c = sf * ld<F32>(c0, n * 128 + t) + si * tanhf(gg);
  float h = so * tanhf(c);
  hs[t] = h;
  __syncthreads();
  if (t < 120) {
    float a = 0.f;
#pragma unroll 4
    for (int k = 0; k < 128; ++k) a += hs[k] * ld<F32>(Wout, t * 128 + k);
    a += ld<F32>(bout, t);
    int kk = t / 20, mm = t - kk * 20;
    int oi = kk * (1024 * 20) + n * 20 + mm;
    if (F32) ((float*)out)[oi] = a;
    else     ((bf16*)out)[oi] = __float2bfloat16(a);
  }
}

__global__ __launch_bounds__(128) void k_lstm_out(const float* gates,
                                                  const void* c0, const void* Wout,
                                                  const void* bout, void* out,
                                                  const int* flag) {
  if (*flag) lstm_body<true>(gates, c0, Wout, bout, out);
  else       lstm_body<false>(gates, c0, Wout, bout, out);
}

// ---------------------------------------------------------------------------
extern "C" void kernel_launch(void* const* d_in, const int* in_sizes, int n_in,
                              void* d_out, int out_size, void* d_ws, size_t ws_size,
                              hipStream_t stream) {
  const void* xabs = d_in[0];
  const void* h0   = d_in[1];
  const void* c0   = d_in[2];
  const void* Wemb = d_in[3];
  const void* bemb = d_in[4];
  const void* Wsoc = d_in[5];
  const void* bsoc = d_in[6];
  const void* Wih  = d_in[7];
  const void* Whh  = d_in[8];
  const void* bih  = d_in[9];
  const void* bhh  = d_in[10];
  const void* Wout = d_in[11];
  const void* bout = d_in[12];

  // Workspace layout: [flag int | pad to 256B | Z f32 16MB | X f32 1MB | gates f32 2MB]
  int* flag    = (int*)d_ws;
  float* Z     = (float*)((char*)d_ws + 256);
  float* X     = Z + (size_t)1024 * 4096;
  float* gates = X + (size_t)1024 * 256;

  k_detect<<<dim3(1), dim3(128), 0, stream>>>(xabs, flag);
  k_zgemm<<<dim3(16, 64), dim3(256), 0, stream>>>(h0, Wsoc, Z, flag);
  k_gather<<<dim3(256), dim3(256), 0, stream>>>(xabs, h0, Wemb, bemb, bsoc, Z, X, flag);
  k_gates<<<dim3(16, 8), dim3(256), 0, stream>>>(X, Wih, Whh, bih, bhh, gates, flag);
  k_lstm_out<<<dim3(1024), dim3(128), 0, stream>>>(gates, c0, Wout, bout, d_out, flag);
}

// Round 3
// 164.090 us; speedup vs baseline: 1.3066x; 1.3066x over previous
//
#include <hip/hip_runtime.h>
#include <hip/hip_bf16.h>
#include <math.h>

typedef __hip_bfloat16 bf16;

__device__ __forceinline__ float b2f(bf16 v) { return __bfloat162float(v); }

template <bool F32>
__device__ __forceinline__ float ld(const void* p, int i) {
  if (F32) return ((const float*)p)[i];
  return b2f(((const bf16*)p)[i]);
}

__device__ __forceinline__ float sigm(float x) {
  return 0.5f * (1.0f + tanhf(0.5f * x));  // saturates cleanly, no inf
}

// ---------------------------------------------------------------------------
// K0: dtype detection. bf16 coords lie in [0,1) -> all u16 have small
// exponents. f32 low half-words are random mantissa bits -> huge exponents
// appear with overwhelming probability. flag = 1 -> f32, 0 -> bf16.
// ---------------------------------------------------------------------------
__global__ void k_detect(const void* xabs, int* flag) {
  __shared__ int hit;
  if (threadIdx.x == 0) hit = 0;
  __syncthreads();
  unsigned short v = ((const unsigned short*)xabs)[threadIdx.x];  // 128 u16s
  int ex = (v >> 7) & 0xFF;
  if (ex >= 0x93) atomicOr(&hit, 1);
  __syncthreads();
  if (threadIdx.x == 0) *flag = hit ? 1 : 0;
}

// ---------------------------------------------------------------------------
// K1: Z[m, g*64+e] = sum_d h0[m,d] * Wsoc[e, g*128+d], stored as bf16.
// grid (16 m-tiles, 64 g), block 256, 64x64 tile, 4x4 microtile,
// K chunked in 64s so LDS = 2*64*68*4 = 34 KB.
// ---------------------------------------------------------------------------
template <bool F32>
__device__ __forceinline__ void zgemm_body(const void* h0, const void* Wsoc,
                                           bf16* __restrict__ Z) {
  const int mt = blockIdx.x;  // 0..15
  const int g  = blockIdx.y;  // 0..63
  __shared__ __align__(16) float Asm[64][68];  // [d][m]
  __shared__ __align__(16) float Bsm[64][68];  // [d][e]
  const int tid = threadIdx.x;
  const int tm = tid & 15, te = tid >> 4;
  float acc[4][4] = {};
  for (int dc = 0; dc < 128; dc += 64) {
    for (int idx = tid; idx < 64 * 64; idx += 256) {
      int r = idx >> 6, d = idx & 63;
      Asm[d][r] = ld<F32>(h0, (mt * 64 + r) * 128 + dc + d);
      Bsm[d][r] = ld<F32>(Wsoc, r * 8192 + g * 128 + dc + d);
    }
    __syncthreads();
    for (int d = 0; d < 64; ++d) {
      float4 a = *reinterpret_cast<const float4*>(&Asm[d][tm * 4]);
      float4 b = *reinterpret_cast<const float4*>(&Bsm[d][te * 4]);
      float av[4] = {a.x, a.y, a.z, a.w};
      float bv[4] = {b.x, b.y, b.z, b.w};
#pragma unroll
      for (int i = 0; i < 4; ++i)
#pragma unroll
        for (int j = 0; j < 4; ++j) acc[i][j] += av[i] * bv[j];
    }
    __syncthreads();
  }
  const int m0 = mt * 64 + tm * 4;
  const int e0 = g * 64 + te * 4;
#pragma unroll
  for (int i = 0; i < 4; ++i) {
    bf16 tmp[4];
#pragma unroll
    for (int j = 0; j < 4; ++j) tmp[j] = __float2bfloat16(acc[i][j]);
    *reinterpret_cast<uint2*>(&Z[(size_t)(m0 + i) * 4096 + e0]) =
        *reinterpret_cast<uint2*>(tmp);
  }
}

__global__ __launch_bounds__(256) void k_zgemm(const void* h0, const void* Wsoc,
                                               bf16* Z, const int* flag) {
  if (*flag) zgemm_body<true>(h0, Wsoc, Z);
  else       zgemm_body<false>(h0, Wsoc, Z);
}

// ---------------------------------------------------------------------------
// K2: one block (4 waves) per n. Phase 1: compact valid (m,cell) pairs into
// an LDS list. Phase 2: unrolled drain, 4 independent Z loads in flight per
// wave. Phase 3: reduce 4 partials, fuse embedding, pack X.
// ---------------------------------------------------------------------------
template <bool F32>
__device__ __forceinline__ void gather_body(const void* xabs, const void* h0,
                                            const void* Wemb, const void* bemb,
                                            const void* bsoc,
                                            const bf16* __restrict__ Z,
                                            float* __restrict__ X) {
  const int n = blockIdx.x;
  const int tid = threadIdx.x;
  const int wave = tid >> 6, lane = tid & 63;
  __shared__ int cnt;
  __shared__ int list[1024];
  __shared__ float part[4][64];
  if (tid == 0) cnt = 0;
  __syncthreads();

  const float xn = ld<F32>(xabs, 2 * n);
  const float yn = ld<F32>(xabs, 2 * n + 1);
  const float tx = xn - 0.2f, ty = yn - 0.2f;

#pragma unroll
  for (int c = 0; c < 4; ++c) {
    const int m = c * 256 + tid;
    float dx = ld<F32>(xabs, 2 * m) - tx;
    float dy = ld<F32>(xabs, 2 * m + 1) - ty;
    int cx = (int)floorf(dx / 0.4f * 8.0f);
    int cy = (int)floorf(dy / 0.4f * 8.0f);
    bool valid = (dx >= 0.f) & (dx < 0.4f) & (dy >= 0.f) & (dy < 0.4f) &
                 (cx >= 0) & (cx < 8) & (cy >= 0) & (cy < 8) & (m != n);
    int cell = cx + cy * 8;
    unsigned long long msk = __ballot(valid);
    int tot = __popcll(msk);
    int base = 0;
    if (lane == 0 && tot) base = atomicAdd(&cnt, tot);
    base = __shfl(base, 0);
    if (valid) {
      int pos = base + __popcll(msk & ((1ull << lane) - 1ull));
      list[pos] = (m << 6) | cell;
    }
  }
  __syncthreads();
  const int total = cnt;

  float a0 = 0.f, a1 = 0.f, a2 = 0.f, a3 = 0.f;
  int i = wave;
  for (; i + 12 < total; i += 16) {
    int e0 = list[i], e1 = list[i + 4], e2 = list[i + 8], e3 = list[i + 12];
    float v0 = b2f(Z[(size_t)(e0 >> 6) * 4096 + (e0 & 63) * 64 + lane]);
    float v1 = b2f(Z[(size_t)(e1 >> 6) * 4096 + (e1 & 63) * 64 + lane]);
    float v2 = b2f(Z[(size_t)(e2 >> 6) * 4096 + (e2 & 63) * 64 + lane]);
    float v3 = b2f(Z[(size_t)(e3 >> 6) * 4096 + (e3 & 63) * 64 + lane]);
    a0 += v0; a1 += v1; a2 += v2; a3 += v3;
  }
  for (; i < total; i += 4) {
    int e0 = list[i];
    a0 += b2f(Z[(size_t)(e0 >> 6) * 4096 + (e0 & 63) * 64 + lane]);
  }
  part[wave][lane] = (a0 + a1) + (a2 + a3);
  __syncthreads();

  float* Xn = X + (size_t)n * 256;
  if (tid < 64) {
    float pool = part[0][tid] + part[1][tid] + part[2][tid] + part[3][tid];
    pool = fmaxf(pool + ld<F32>(bsoc, tid), 0.f);
    Xn[64 + tid] = pool;
    float emb = fmaxf(ld<F32>(Wemb, tid * 2) * xn +
                          ld<F32>(Wemb, tid * 2 + 1) * yn + ld<F32>(bemb, tid),
                      0.f);
    Xn[tid] = emb;
  } else if (tid < 192) {
    Xn[128 + (tid - 64)] = ld<F32>(h0, n * 128 + (tid - 64));
  }
}

__global__ __launch_bounds__(256) void k_gather(const void* xabs, const void* h0,
                                                const void* Wemb, const void* bemb,
                                                const void* bsoc, const bf16* Z,
                                                float* X, const int* flag) {
  if (*flag) gather_body<true>(xabs, h0, Wemb, bemb, bsoc, Z, X);
  else       gather_body<false>(xabs, h0, Wemb, bemb, bsoc, Z, X);
}

// ---------------------------------------------------------------------------
// K3: gates[1024x512] = X[1024x256] @ Bcat[256x512] + (b_ih + b_hh)
// Bcat[k,j] = W_ih[j,k] (k<128) else W_hh[j,k-128].  W_ih is [512,128].
// ---------------------------------------------------------------------------
template <bool F32>
__device__ __forceinline__ void gates_body(const float* __restrict__ X,
                                           const void* Wih, const void* Whh,
                                           const void* bih, const void* bhh,
                                           float* __restrict__ gates) {
  const int nt = blockIdx.x;  // 0..15
  const int jt = blockIdx.y;  // 0..7
  __shared__ __align__(16) float Asm[64][68];  // [k][n]
  __shared__ __align__(16) float Bsm[64][68];  // [k][j]
  const int tid = threadIdx.x;
  const int tm = tid & 15, te = tid >> 4;
  float acc[4][4] = {};
  for (int kc = 0; kc < 256; kc += 64) {
    for (int idx = tid; idx < 64 * 64; idx += 256) {
      int r = idx >> 6, k = idx & 63;
      Asm[k][r] = X[(size_t)(nt * 64 + r) * 256 + kc + k];
      int j = jt * 64 + r;
      int kg = kc + k;
      Bsm[k][r] = (kg < 128) ? ld<F32>(Wih, j * 128 + kg)
                             : ld<F32>(Whh, j * 128 + kg - 128);
    }
    __syncthreads();
    for (int k = 0; k < 64; ++k) {
      float4 a = *reinterpret_cast<const float4*>(&Asm[k][tm * 4]);
      float4 b = *reinterpret_cast<const float4*>(&Bsm[k][te * 4]);
      float av[4] = {a.x, a.y, a.z, a.w};
      float bv[4] = {b.x, b.y, b.z, b.w};
#pragma unroll
      for (int i = 0; i < 4; ++i)
#pragma unroll
        for (int j = 0; j < 4; ++j) acc[i][j] += av[i] * bv[j];
    }
    __syncthreads();
  }
  const int n0 = nt * 64 + tm * 4;
  const int j0 = jt * 64 + te * 4;
  float bsum[4];
#pragma unroll
  for (int j = 0; j < 4; ++j)
    bsum[j] = ld<F32>(bih, j0 + j) + ld<F32>(bhh, j0 + j);
#pragma unroll
  for (int i = 0; i < 4; ++i) {
    float4 v = make_float4(acc[i][0] + bsum[0], acc[i][1] + bsum[1],
                           acc[i][2] + bsum[2], acc[i][3] + bsum[3]);
    *reinterpret_cast<float4*>(&gates[(size_t)(n0 + i) * 512 + j0]) = v;
  }
}

__global__ __launch_bounds__(256) void k_gates(const float* X, const void* Wih,
                                               const void* Whh, const void* bih,
                                               const void* bhh, float* gates,
                                               const int* flag) {
  if (*flag) gates_body<true>(X, Wih, Whh, bih, bhh, gates);
  else       gates_body<false>(X, Wih, Whh, bih, bhh, gates);
}

// ---------------------------------------------------------------------------
// K4: LSTM elementwise + final = h @ W_out^T + b_out -> 6 chunks [1024,20].
// ---------------------------------------------------------------------------
template <bool F32>
__device__ __forceinline__ void lstm_body(const float* __restrict__ gates,
                                          const void* c0, const void* Wout,
                                          const void* bout, void* out) {
  const int n = blockIdx.x;
  const int t = threadIdx.x;  // 0..127
  __shared__ float hs[128];
  const float* gn = gates + (size_t)n * 512;
  float ig = gn[t], fg = gn[128 + t], gg = gn[256 + t], og = gn[384 + t];
  float si = sigm(ig), sf = sigm(fg), so = sigm(og);
  float c = sf * ld<F32>(c0, n * 128 + t) + si * tanhf(gg);
  float h = so * tanhf(c);
  hs[t] = h;
  __syncthreads();
  if (t < 120) {
    float a = 0.f;
#pragma unroll 4
    for (int k = 0; k < 128; ++k) a += hs[k] * ld<F32>(Wout, t * 128 + k);
    a += ld<F32>(bout, t);
    int kk = t / 20, mm = t - kk * 20;
    int oi = kk * (1024 * 20) + n * 20 + mm;
    if (F32) ((float*)out)[oi] = a;
    else     ((bf16*)out)[oi] = __float2bfloat16(a);
  }
}

__global__ __launch_bounds__(128) void k_lstm_out(const float* gates,
                                                  const void* c0, const void* Wout,
                                                  const void* bout, void* out,
                                                  const int* flag) {
  if (*flag) lstm_body<true>(gates, c0, Wout, bout, out);
  else       lstm_body<false>(gates, c0, Wout, bout, out);
}

// ---------------------------------------------------------------------------
extern "C" void kernel_launch(void* const* d_in, const int* in_sizes, int n_in,
                              void* d_out, int out_size, void* d_ws, size_t ws_size,
                              hipStream_t stream) {
  const void* xabs = d_in[0];
  const void* h0   = d_in[1];
  const void* c0   = d_in[2];
  const void* Wemb = d_in[3];
  const void* bemb = d_in[4];
  const void* Wsoc = d_in[5];
  const void* bsoc = d_in[6];
  const void* Wih  = d_in[7];
  const void* Whh  = d_in[8];
  const void* bih  = d_in[9];
  const void* bhh  = d_in[10];
  const void* Wout = d_in[11];
  const void* bout = d_in[12];

  // Workspace: [flag | pad 256B | Z bf16 8MB | X f32 1MB | gates f32 2MB]
  int* flag    = (int*)d_ws;
  bf16* Z      = (bf16*)((char*)d_ws + 256);
  float* X     = (float*)((char*)d_ws + 256 + (size_t)1024 * 4096 * 2);
  float* gates = X + (size_t)1024 * 256;

  k_detect<<<dim3(1), dim3(128), 0, stream>>>(xabs, flag);
  k_zgemm<<<dim3(16, 64), dim3(256), 0, stream>>>(h0, Wsoc, Z, flag);
  k_gather<<<dim3(1024), dim3(256), 0, stream>>>(xabs, h0, Wemb, bemb, bsoc, Z, X, flag);
  k_gates<<<dim3(16, 8), dim3(256), 0, stream>>>(X, Wih, Whh, bih, bhh, gates, flag);
  k_lstm_out<<<dim3(1024), dim3(128), 0, stream>>>(gates, c0, Wout, bout, d_out, flag);
}

// Round 4
// 147.274 us; speedup vs baseline: 1.4558x; 1.1142x over previous
//
#include <hip/hip_runtime.h>
#include <hip/hip_bf16.h>
#include <math.h>

typedef __hip_bfloat16 bf16;
typedef short s8v __attribute__((ext_vector_type(8)));   // 8 bf16 (4 VGPRs)
typedef float f4v __attribute__((ext_vector_type(4)));   // MFMA acc

__device__ __forceinline__ float b2f(bf16 v) { return __bfloat162float(v); }

template <bool F32>
__device__ __forceinline__ float ld(const void* p, int i) {
  if (F32) return ((const float*)p)[i];
  return b2f(((const bf16*)p)[i]);
}

__device__ __forceinline__ float sigm(float x) {
  return 0.5f * (1.0f + tanhf(0.5f * x));  // saturates cleanly, no inf
}

// Inline dtype detect: bf16 coords in [0,1) -> all halfwords have small
// exponent. f32 low halfwords are random mantissa bits -> bf16-exponent
// >= 0x93 appears w.p. ~0.43/halfword; P(miss over 32) ~ 1.5e-8.
// Wave-uniform result; call before any divergence.
__device__ __forceinline__ bool detect_f32(const void* xabs) {
  unsigned short v = ((const unsigned short*)xabs)[threadIdx.x & 63];
  int ex = (v >> 7) & 0xFF;
  return __ballot(ex >= 0x93) != 0ull;
}

// ---------------------------------------------------------------------------
// K1: Z[m, g*64+e] = sum_d h0[m,d] * Wsoc[e, g*128+d], stored bf16.
// bf16 path: MFMA 16x16x32. grid 1024 x 256thr; block b: mt = b&63 (16 m),
// wave w handles g = (b>>6)*4 + w, i.e. Z[mt*16..+16][g*64..+64], K=128.
// ---------------------------------------------------------------------------
__device__ void zgemm_f32_body(const void* h0, const void* Wsoc,
                               bf16* __restrict__ Z) {
  const int mt = blockIdx.x & 15;
  const int g  = blockIdx.x >> 4;
  __shared__ __align__(16) float Asm[64][68];
  __shared__ __align__(16) float Bsm[64][68];
  const int tid = threadIdx.x;
  const int tm = tid & 15, te = tid >> 4;
  float acc[4][4] = {};
  for (int dc = 0; dc < 128; dc += 64) {
    for (int idx = tid; idx < 64 * 64; idx += 256) {
      int r = idx >> 6, d = idx & 63;
      Asm[d][r] = ld<true>(h0, (mt * 64 + r) * 128 + dc + d);
      Bsm[d][r] = ld<true>(Wsoc, r * 8192 + g * 128 + dc + d);
    }
    __syncthreads();
    for (int d = 0; d < 64; ++d) {
      float4 a = *reinterpret_cast<const float4*>(&Asm[d][tm * 4]);
      float4 b = *reinterpret_cast<const float4*>(&Bsm[d][te * 4]);
      float av[4] = {a.x, a.y, a.z, a.w};
      float bv[4] = {b.x, b.y, b.z, b.w};
#pragma unroll
      for (int i = 0; i < 4; ++i)
#pragma unroll
        for (int j = 0; j < 4; ++j) acc[i][j] += av[i] * bv[j];
    }
    __syncthreads();
  }
  const int m0 = mt * 64 + tm * 4, e0 = g * 64 + te * 4;
#pragma unroll
  for (int i = 0; i < 4; ++i) {
    bf16 tmp[4];
#pragma unroll
    for (int j = 0; j < 4; ++j) tmp[j] = __float2bfloat16(acc[i][j]);
    *reinterpret_cast<uint2*>(&Z[(size_t)(m0 + i) * 4096 + e0]) =
        *reinterpret_cast<uint2*>(tmp);
  }
}

__global__ __launch_bounds__(256) void k_zgemm(const void* h0v, const void* Wsocv,
                                               bf16* __restrict__ Z,
                                               const void* xabs) {
  if (detect_f32(xabs)) {  // f32 fallback: 16x64 decode of 1024-block grid
    if (blockIdx.x < 1024) zgemm_f32_body(h0v, Wsocv, Z);
    return;
  }
  const bf16* h0 = (const bf16*)h0v;
  const bf16* Wsoc = (const bf16*)Wsocv;
  const int wave = threadIdx.x >> 6, lane = threadIdx.x & 63;
  const int mt = blockIdx.x & 63;
  const int g  = (blockIdx.x >> 6) * 4 + wave;
  const int r16 = lane & 15, quad = lane >> 4;
  // A fragments: A[m = r16][k = kq*32 + quad*8 + j]
  s8v afr[4];
#pragma unroll
  for (int kq = 0; kq < 4; ++kq)
    afr[kq] = *reinterpret_cast<const s8v*>(
        &h0[(mt * 16 + r16) * 128 + kq * 32 + quad * 8]);
  f4v acc[4] = {{0.f, 0.f, 0.f, 0.f}, {0.f, 0.f, 0.f, 0.f},
                {0.f, 0.f, 0.f, 0.f}, {0.f, 0.f, 0.f, 0.f}};
#pragma unroll
  for (int t = 0; t < 4; ++t) {  // e-subtile: e_local = t*16 + r16
#pragma unroll
    for (int kq = 0; kq < 4; ++kq) {
      s8v bfr = *reinterpret_cast<const s8v*>(
          &Wsoc[(size_t)(t * 16 + r16) * 8192 + g * 128 + kq * 32 + quad * 8]);
      acc[t] = __builtin_amdgcn_mfma_f32_16x16x32_bf16(afr[kq], bfr, acc[t],
                                                       0, 0, 0);
    }
  }
  // D[m = quad*4 + reg][n = r16]
#pragma unroll
  for (int t = 0; t < 4; ++t)
#pragma unroll
    for (int reg = 0; reg < 4; ++reg)
      Z[(size_t)(mt * 16 + quad * 4 + reg) * 4096 + g * 64 + t * 16 + r16] =
          __float2bfloat16(acc[t][reg]);
}

// ---------------------------------------------------------------------------
// K2: one block (4 waves) per n. Compact valid (m,cell) pairs into LDS list,
// drain with 4-deep ILP, reduce, fuse embedding, pack X[n,0:256].
// ---------------------------------------------------------------------------
template <bool F32>
__device__ __forceinline__ void gather_body(const void* xabs, const void* h0,
                                            const void* Wemb, const void* bemb,
                                            const void* bsoc,
                                            const bf16* __restrict__ Z,
                                            float* __restrict__ X) {
  const int n = blockIdx.x;
  const int tid = threadIdx.x;
  const int wave = tid >> 6, lane = tid & 63;
  __shared__ int cnt;
  __shared__ int list[1024];
  __shared__ float part[4][64];
  if (tid == 0) cnt = 0;
  __syncthreads();

  const float xn = ld<F32>(xabs, 2 * n);
  const float yn = ld<F32>(xabs, 2 * n + 1);
  const float tx = xn - 0.2f, ty = yn - 0.2f;

#pragma unroll
  for (int c = 0; c < 4; ++c) {
    const int m = c * 256 + tid;
    float dx = ld<F32>(xabs, 2 * m) - tx;
    float dy = ld<F32>(xabs, 2 * m + 1) - ty;
    int cx = (int)floorf(dx / 0.4f * 8.0f);
    int cy = (int)floorf(dy / 0.4f * 8.0f);
    bool valid = (dx >= 0.f) & (dx < 0.4f) & (dy >= 0.f) & (dy < 0.4f) &
                 (cx >= 0) & (cx < 8) & (cy >= 0) & (cy < 8) & (m != n);
    int cell = cx + cy * 8;
    unsigned long long msk = __ballot(valid);
    int tot = __popcll(msk);
    int base = 0;
    if (lane == 0 && tot) base = atomicAdd(&cnt, tot);
    base = __shfl(base, 0);
    if (valid) {
      int pos = base + __popcll(msk & ((1ull << lane) - 1ull));
      list[pos] = (m << 6) | cell;
    }
  }
  __syncthreads();
  const int total = cnt;

  float a0 = 0.f, a1 = 0.f, a2 = 0.f, a3 = 0.f;
  int i = wave;
  for (; i + 12 < total; i += 16) {
    int e0 = list[i], e1 = list[i + 4], e2 = list[i + 8], e3 = list[i + 12];
    float v0 = b2f(Z[(size_t)(e0 >> 6) * 4096 + (e0 & 63) * 64 + lane]);
    float v1 = b2f(Z[(size_t)(e1 >> 6) * 4096 + (e1 & 63) * 64 + lane]);
    float v2 = b2f(Z[(size_t)(e2 >> 6) * 4096 + (e2 & 63) * 64 + lane]);
    float v3 = b2f(Z[(size_t)(e3 >> 6) * 4096 + (e3 & 63) * 64 + lane]);
    a0 += v0; a1 += v1; a2 += v2; a3 += v3;
  }
  for (; i < total; i += 4) {
    int e0 = list[i];
    a0 += b2f(Z[(size_t)(e0 >> 6) * 4096 + (e0 & 63) * 64 + lane]);
  }
  part[wave][lane] = (a0 + a1) + (a2 + a3);
  __syncthreads();

  float* Xn = X + (size_t)n * 256;
  if (tid < 64) {
    float pool = part[0][tid] + part[1][tid] + part[2][tid] + part[3][tid];
    pool = fmaxf(pool + ld<F32>(bsoc, tid), 0.f);
    Xn[64 + tid] = pool;
    float emb = fmaxf(ld<F32>(Wemb, tid * 2) * xn +
                          ld<F32>(Wemb, tid * 2 + 1) * yn + ld<F32>(bemb, tid),
                      0.f);
    Xn[tid] = emb;
  } else if (tid < 192) {
    Xn[128 + (tid - 64)] = ld<F32>(h0, n * 128 + (tid - 64));
  }
}

__global__ __launch_bounds__(256) void k_gather(const void* xabs, const void* h0,
                                                const void* Wemb, const void* bemb,
                                                const void* bsoc, const bf16* Z,
                                                float* X) {
  if (detect_f32(xabs)) gather_body<true>(xabs, h0, Wemb, bemb, bsoc, Z, X);
  else                  gather_body<false>(xabs, h0, Wemb, bemb, bsoc, Z, X);
}

// ---------------------------------------------------------------------------
// K3: gates[1024x512] = X[1024x256] @ Bcat[256x512] + (b_ih + b_hh)
// Bcat[k,j] = W_ih[j,k] (k<128) else W_hh[j,k-128].
// grid (16 nt, 16 jt) = 256 blocks (1/CU), 64x32 tile, 4x2 microtile.
// ---------------------------------------------------------------------------
template <bool F32>
__device__ __forceinline__ void gates_body(const float* __restrict__ X,
                                           const void* Wih, const void* Whh,
                                           const void* bih, const void* bhh,
                                           float* __restrict__ gates) {
  const int nt = blockIdx.x;  // 0..15
  const int jt = blockIdx.y;  // 0..15
  __shared__ __align__(16) float Asm[64][68];  // [k][n]
  __shared__ __align__(16) float Bsm[64][36];  // [k][j]
  const int tid = threadIdx.x;
  const int tm = tid & 15, te = tid >> 4;
  float acc[4][2] = {};
  for (int kc = 0; kc < 256; kc += 64) {
    for (int idx = tid; idx < 64 * 64; idx += 256) {
      int r = idx >> 6, k = idx & 63;
      Asm[k][r] = X[(size_t)(nt * 64 + r) * 256 + kc + k];
    }
    for (int idx = tid; idx < 32 * 64; idx += 256) {
      int r = idx >> 6, k = idx & 63;
      int j = jt * 32 + r, kg = kc + k;
      Bsm[k][r] = (kg < 128) ? ld<F32>(Wih, j * 128 + kg)
                             : ld<F32>(Whh, j * 128 + kg - 128);
    }
    __syncthreads();
    for (int k = 0; k < 64; ++k) {
      float4 a = *reinterpret_cast<const float4*>(&Asm[k][tm * 4]);
      float2 b = *reinterpret_cast<const float2*>(&Bsm[k][te * 2]);
      float av[4] = {a.x, a.y, a.z, a.w};
      float bv[2] = {b.x, b.y};
#pragma unroll
      for (int i = 0; i < 4; ++i)
#pragma unroll
        for (int j = 0; j < 2; ++j) acc[i][j] += av[i] * bv[j];
    }
    __syncthreads();
  }
  const int n0 = nt * 64 + tm * 4;
  const int j0 = jt * 32 + te * 2;
  float bs0 = ld<F32>(bih, j0) + ld<F32>(bhh, j0);
  float bs1 = ld<F32>(bih, j0 + 1) + ld<F32>(bhh, j0 + 1);
#pragma unroll
  for (int i = 0; i < 4; ++i) {
    float2 v = make_float2(acc[i][0] + bs0, acc[i][1] + bs1);
    *reinterpret_cast<float2*>(&gates[(size_t)(n0 + i) * 512 + j0]) = v;
  }
}

__global__ __launch_bounds__(256) void k_gates(const float* X, const void* Wih,
                                               const void* Whh, const void* bih,
                                               const void* bhh, float* gates,
                                               const void* xabs) {
  if (detect_f32(xabs)) gates_body<true>(X, Wih, Whh, bih, bhh, gates);
  else                  gates_body<false>(X, Wih, Whh, bih, bhh, gates);
}

// ---------------------------------------------------------------------------
// K4: LSTM elementwise + final = h @ W_out^T + b_out -> 6 chunks [1024,20].
// ---------------------------------------------------------------------------
template <bool F32>
__device__ __forceinline__ void lstm_body(const float* __restrict__ gates,
                                          const void* c0, const void* Wout,
                                          const void* bout, void* out) {
  const int n = blockIdx.x;
  const int t = threadIdx.x;  // 0..127
  __shared__ float hs[128];
  const float* gn = gates + (size_t)n * 512;
  float ig = gn[t], fg = gn[128 + t], gg = gn[256 + t], og = gn[384 + t];
  float si = sigm(ig), sf = sigm(fg), so = sigm(og);
  float c = sf * ld<F32>(c0, n * 128 + t) + si * tanhf(gg);
  float h = so * tanhf(c);
  hs[t] = h;
  __syncthreads();
  if (t < 120) {
    float a = 0.f;
#pragma unroll 4
    for (int k = 0; k < 128; ++k) a += hs[k] * ld<F32>(Wout, t * 128 + k);
    a += ld<F32>(bout, t);
    int kk = t / 20, mm = t - kk * 20;
    int oi = kk * (1024 * 20) + n * 20 + mm;
    if (F32) ((float*)out)[oi] = a;
    else     ((bf16*)out)[oi] = __float2bfloat16(a);
  }
}

__global__ __launch_bounds__(128) void k_lstm_out(const float* gates,
                                                  const void* c0, const void* Wout,
                                                  const void* bout, void* out,
                                                  const void* xabs) {
  if (detect_f32(xabs)) lstm_body<true>(gates, c0, Wout, bout, out);
  else                  lstm_body<false>(gates, c0, Wout, bout, out);
}

// ---------------------------------------------------------------------------
extern "C" void kernel_launch(void* const* d_in, const int* in_sizes, int n_in,
                              void* d_out, int out_size, void* d_ws, size_t ws_size,
                              hipStream_t stream) {
  const void* xabs = d_in[0];
  const void* h0   = d_in[1];
  const void* c0   = d_in[2];
  const void* Wemb = d_in[3];
  const void* bemb = d_in[4];
  const void* Wsoc = d_in[5];
  const void* bsoc = d_in[6];
  const void* Wih  = d_in[7];
  const void* Whh  = d_in[8];
  const void* bih  = d_in[9];
  const void* bhh  = d_in[10];
  const void* Wout = d_in[11];
  const void* bout = d_in[12];

  // Workspace: [Z bf16 8MB | X f32 1MB | gates f32 2MB]
  bf16* Z      = (bf16*)d_ws;
  float* X     = (float*)((char*)d_ws + (size_t)1024 * 4096 * 2);
  float* gates = X + (size_t)1024 * 256;

  k_zgemm<<<dim3(1024), dim3(256), 0, stream>>>(h0, Wsoc, Z, xabs);
  k_gather<<<dim3(1024), dim3(256), 0, stream>>>(xabs, h0, Wemb, bemb, bsoc, Z, X);
  k_gates<<<dim3(16, 16), dim3(256), 0, stream>>>(X, Wih, Whh, bih, bhh, gates, xabs);
  k_lstm_out<<<dim3(1024), dim3(128), 0, stream>>>(gates, c0, Wout, bout, d_out, xabs);
}